// Round 1
// baseline (2772.541 us; speedup 1.0000x reference)
//
#include <hip/hip_runtime.h>
#include <hip/hip_bf16.h>
#include <cstddef>

// Problem constants
#define BATCH 32
#define TSTEPS 20
#define IN_DIM 3
#define WIDTH 256
#define HID 64
#define FC1_IN 327680   // HID * TSTEPS * WIDTH
#define FC1_OUT 512
#define OUT_DIM 3

__device__ __forceinline__ float sigm(float x) {
    return 1.0f / (1.0f + __expf(-x));
}
__device__ __forceinline__ float tanh_fast(float x) {
    // 1 - 2/(e^{2x}+1): saturates cleanly, no NaN for large |x|
    return 1.0f - 2.0f / (__expf(2.0f * x) + 1.0f);
}

// Fused ConvLSTM step: gates = conv1d_w3(z) + b, z = concat(x_t, h_prev) over channels.
// Only kh=1 of the 3x3 kernel contributes (H=1 with SAME padding).
// Grid: (32 b, 4 wtiles, 4 hctiles). Block: 256 = 16 hc x 16 wgroups (4 w each).
template <int CINX>
__global__ __launch_bounds__(256) void lstm_step(
    const float* __restrict__ x, int xbs,          // x_t: [B][CINX][256], batch stride xbs
    const float* __restrict__ hprev,               // [B][64][256]
    float* __restrict__ hnew,                      // [B][64][256]
    float* __restrict__ cst,                       // [B][64][256], updated in place
    const float* __restrict__ cw,                  // [256][CIN][3][3]
    const float* __restrict__ cb,                  // [256]
    float* __restrict__ seqout, int seqbs)         // optional flat h output (may be null)
{
    constexpr int CIN = CINX + HID;
    __shared__ float zt[CIN * 66];  // zt[ci][j], j=0..65 maps to w = w0 + j - 1

    const int b   = blockIdx.x;
    const int w0  = blockIdx.y * 64;
    const int hc0 = blockIdx.z * 16;
    const int tid = threadIdx.x;

    // Stage z tile into LDS
    for (int idx = tid; idx < CIN * 66; idx += 256) {
        int ci = idx / 66;
        int j  = idx - ci * 66;
        int wg = w0 + j - 1;
        float v = 0.0f;
        if (wg >= 0 && wg < WIDTH) {
            v = (ci < CINX) ? x[(size_t)b * xbs + ci * WIDTH + wg]
                            : hprev[((size_t)b * HID + (ci - CINX)) * WIDTH + wg];
        }
        zt[idx] = v;
    }
    __syncthreads();

    const int hc = hc0 + (tid >> 4);
    const int wq = (tid & 15) * 4;   // offset within the 64-wide tile

    float acc[4][4];
#pragma unroll
    for (int g = 0; g < 4; ++g) {
        float bv = cb[g * 64 + hc];
#pragma unroll
        for (int wi = 0; wi < 4; ++wi) acc[g][wi] = bv;
    }

    // weight row bases: w[co][ci][1][kw], co = g*64+hc
    size_t wrow[4];
#pragma unroll
    for (int g = 0; g < 4; ++g)
        wrow[g] = ((size_t)(g * 64 + hc) * CIN) * 9 + 3;  // +3 selects kh=1

    for (int ci = 0; ci < CIN; ++ci) {
        float zv[6];
#pragma unroll
        for (int j = 0; j < 6; ++j) zv[j] = zt[ci * 66 + wq + j];
#pragma unroll
        for (int g = 0; g < 4; ++g) {
            const float* wp = cw + wrow[g] + (size_t)ci * 9;
            float wa = wp[0], wb = wp[1], wc = wp[2];
#pragma unroll
            for (int wi = 0; wi < 4; ++wi)
                acc[g][wi] += wa * zv[wi] + wb * zv[wi + 1] + wc * zv[wi + 2];
        }
    }

    // Gate nonlinearities + state update. i=g0, f=g1, o=g2, g=g3.
#pragma unroll
    for (int wi = 0; wi < 4; ++wi) {
        int w = w0 + wq + wi;
        float iv = sigm(acc[0][wi]);
        float fv = sigm(acc[1][wi]);
        float ov = sigm(acc[2][wi]);
        float gv = tanh_fast(acc[3][wi]);
        size_t idx = ((size_t)b * HID + hc) * WIDTH + w;
        float cv = cst[idx];
        float cn = fv * cv + iv * gv;
        cst[idx] = cn;
        float hv = ov * tanh_fast(cn);
        hnew[idx] = hv;
        if (seqout) seqout[(size_t)b * seqbs + hc * WIDTH + w] = hv;
    }
}

// FC1: z[b][n] partial = sum_k fcin[b][k] * w[n][k] over this block's K slice.
// Grid: (256 ksplits, 8 ntiles). Block 256 = 32 b-lanes x 8 n-groups; each thread 8 n.
__global__ __launch_bounds__(256) void fc1_kernel(
    const float* __restrict__ a,    // fcin [32][327680]
    const float* __restrict__ w,    // fc1_w [512][327680]
    float* __restrict__ part)       // [256][512][32]
{
    const int K = FC1_IN;
    const int ks = blockIdx.x;       // 0..255
    const int nt = blockIdx.y;       // 0..7
    const int tid = threadIdx.x;
    const int b  = tid & 31;
    const int ng = tid >> 5;         // 0..7
    const int k0 = ks * (K / 256);   // 1280 per split

    float acc[8] = {0.f, 0.f, 0.f, 0.f, 0.f, 0.f, 0.f, 0.f};
    const float* arow = a + (size_t)b * K + k0;
    const float* wr[8];
#pragma unroll
    for (int j = 0; j < 8; ++j)
        wr[j] = w + (size_t)(nt * 64 + ng + 8 * j) * K + k0;

    for (int kk = 0; kk < K / 256; kk += 4) {
        float4 av = *(const float4*)(arow + kk);
#pragma unroll
        for (int j = 0; j < 8; ++j) {
            float4 wv = *(const float4*)(wr[j] + kk);
            acc[j] += av.x * wv.x + av.y * wv.y + av.z * wv.z + av.w * wv.w;
        }
    }
#pragma unroll
    for (int j = 0; j < 8; ++j) {
        int n = nt * 64 + ng + 8 * j;
        part[(size_t)ks * (FC1_OUT * BATCH) + (size_t)n * BATCH + b] = acc[j];
    }
}

// Reduce 256 partials, add bias, ReLU. z1 layout [32][512].
__global__ __launch_bounds__(256) void fc1_reduce(
    const float* __restrict__ part, const float* __restrict__ b1,
    float* __restrict__ z1)
{
    int e = blockIdx.x * 256 + threadIdx.x;  // < 16384
    float s = 0.0f;
    for (int ks = 0; ks < 256; ++ks)
        s += part[(size_t)ks * (FC1_OUT * BATCH) + e];
    int n = e >> 5, b = e & 31;
    float v = s + b1[n];
    z1[(size_t)b * FC1_OUT + n] = v > 0.0f ? v : 0.0f;
}

// FC2 + sigmoid on column 2. out [32][3].
__global__ __launch_bounds__(128) void fc2_kernel(
    const float* __restrict__ z1, const float* __restrict__ w2,
    const float* __restrict__ b2, float* __restrict__ out)
{
    int t = threadIdx.x;
    if (t >= BATCH * OUT_DIM) return;
    int b = t / OUT_DIM, n = t - b * OUT_DIM;
    const float* zr = z1 + (size_t)b * FC1_OUT;
    const float* wr = w2 + (size_t)n * FC1_OUT;
    float acc = b2[n];
    for (int k = 0; k < FC1_OUT; ++k) acc += zr[k] * wr[k];
    if (n == 2) acc = sigm(acc);
    out[(size_t)b * OUT_DIM + n] = acc;
}

extern "C" void kernel_launch(void* const* d_in, const int* in_sizes, int n_in,
                              void* d_out, int out_size, void* d_ws, size_t ws_size,
                              hipStream_t stream) {
    const float* x   = (const float*)d_in[0];
    const float* cw0 = (const float*)d_in[1];
    const float* cb0 = (const float*)d_in[2];
    const float* cw1 = (const float*)d_in[3];
    const float* cb1 = (const float*)d_in[4];
    const float* w1  = (const float*)d_in[5];
    const float* b1  = (const float*)d_in[6];
    const float* w2  = (const float*)d_in[7];
    const float* b2  = (const float*)d_in[8];
    float* out = (float*)d_out;

    float* W = (float*)d_ws;
    const size_t S = (size_t)BATCH * HID * WIDTH;  // 524288 floats per state buffer
    float* h0buf[2] = { W + 0 * S, W + 4 * S };
    float* c0      = W + 1 * S;
    float* h1buf[2] = { W + 2 * S, W + 5 * S };
    float* c1      = W + 3 * S;
    float* fcin    = W + 6 * S;                         // [32][327680]
    float* z1      = fcin + (size_t)BATCH * FC1_IN;     // [32][512]
    float* part    = z1 + (size_t)BATCH * FC1_OUT;      // [256][512][32]

    // Zero initial states: h0_0, c0, h1_0, c1 are the first 4*S floats
    hipMemsetAsync(W, 0, 4 * S * sizeof(float), stream);

    dim3 cgrid(BATCH, 4, 4);
    for (int t = 0; t < TSTEPS; ++t) {
        const float* h0p = h0buf[t & 1];
        float* h0n = h0buf[(t & 1) ^ 1];
        lstm_step<IN_DIM><<<cgrid, 256, 0, stream>>>(
            x + (size_t)t * IN_DIM * WIDTH, TSTEPS * IN_DIM * WIDTH,
            h0p, h0n, c0, cw0, cb0, nullptr, 0);

        const float* h1p = h1buf[t & 1];
        float* h1n = h1buf[(t & 1) ^ 1];
        lstm_step<HID><<<cgrid, 256, 0, stream>>>(
            h0n, HID * WIDTH,
            h1p, h1n, c1, cw1, cb1,
            fcin + (size_t)t * HID * WIDTH, FC1_IN);
    }

    fc1_kernel<<<dim3(256, 8), 256, 0, stream>>>(fcin, w1, part);
    fc1_reduce<<<64, 256, 0, stream>>>(part, b1, z1);
    fc2_kernel<<<1, 128, 0, stream>>>(z1, w2, b2, out);
}

// Round 2
// 1658.720 us; speedup vs baseline: 1.6715x; 1.6715x over previous
//
#include <hip/hip_runtime.h>
#include <hip/hip_bf16.h>
#include <cstddef>

// Problem constants
#define BATCH 32
#define TSTEPS 20
#define IN_DIM 3
#define WIDTH 256
#define HID 64
#define FC1_IN 327680   // HID * TSTEPS * WIDTH
#define FC1_OUT 512
#define OUT_DIM 3

typedef _Float16 half8 __attribute__((ext_vector_type(8)));
typedef float floatx4 __attribute__((ext_vector_type(4)));

__device__ __forceinline__ float sigm(float x) {
    return 1.0f / (1.0f + __expf(-x));
}
__device__ __forceinline__ float tanh_fast(float x) {
    return 1.0f - 2.0f / (__expf(2.0f * x) + 1.0f);
}

// Fused ConvLSTM step: gates = conv1d_w3(z) + b, z = concat(x_t, h_prev).
// Only kh=1 of the 3x3 kernel contributes (H=1 with SAME padding).
// Grid: (32 b, 4 wtiles, 4 hctiles). Block: 256 = 16 hc x 16 wgroups (4 w each).
template <int CINX>
__global__ __launch_bounds__(256) void lstm_step(
    const float* __restrict__ x, int xbs,
    const float* __restrict__ hprev,
    float* __restrict__ hnew,
    float* __restrict__ cst,
    const float* __restrict__ cw,
    const float* __restrict__ cb,
    _Float16* __restrict__ seqout, int seqbs)   // fp16 flat h output (may be null)
{
    constexpr int CIN = CINX + HID;
    __shared__ float zt[CIN * 66];

    const int b   = blockIdx.x;
    const int w0  = blockIdx.y * 64;
    const int hc0 = blockIdx.z * 16;
    const int tid = threadIdx.x;

    for (int idx = tid; idx < CIN * 66; idx += 256) {
        int ci = idx / 66;
        int j  = idx - ci * 66;
        int wg = w0 + j - 1;
        float v = 0.0f;
        if (wg >= 0 && wg < WIDTH) {
            v = (ci < CINX) ? x[(size_t)b * xbs + ci * WIDTH + wg]
                            : hprev[((size_t)b * HID + (ci - CINX)) * WIDTH + wg];
        }
        zt[idx] = v;
    }
    __syncthreads();

    const int hc = hc0 + (tid >> 4);
    const int wq = (tid & 15) * 4;

    float acc[4][4];
#pragma unroll
    for (int g = 0; g < 4; ++g) {
        float bv = cb[g * 64 + hc];
#pragma unroll
        for (int wi = 0; wi < 4; ++wi) acc[g][wi] = bv;
    }

    size_t wrow[4];
#pragma unroll
    for (int g = 0; g < 4; ++g)
        wrow[g] = ((size_t)(g * 64 + hc) * CIN) * 9 + 3;

    for (int ci = 0; ci < CIN; ++ci) {
        float zv[6];
#pragma unroll
        for (int j = 0; j < 6; ++j) zv[j] = zt[ci * 66 + wq + j];
#pragma unroll
        for (int g = 0; g < 4; ++g) {
            const float* wp = cw + wrow[g] + (size_t)ci * 9;
            float wa = wp[0], wb = wp[1], wc = wp[2];
#pragma unroll
            for (int wi = 0; wi < 4; ++wi)
                acc[g][wi] += wa * zv[wi] + wb * zv[wi + 1] + wc * zv[wi + 2];
        }
    }

#pragma unroll
    for (int wi = 0; wi < 4; ++wi) {
        int w = w0 + wq + wi;
        float iv = sigm(acc[0][wi]);
        float fv = sigm(acc[1][wi]);
        float ov = sigm(acc[2][wi]);
        float gv = tanh_fast(acc[3][wi]);
        size_t idx = ((size_t)b * HID + hc) * WIDTH + w;
        float cv = cst[idx];
        float cn = fv * cv + iv * gv;
        cst[idx] = cn;
        float hv = ov * tanh_fast(cn);
        hnew[idx] = hv;
        if (seqout) seqout[(size_t)b * seqbs + hc * WIDTH + w] = (_Float16)hv;
    }
}

// FC1 as fp16 MFMA GEMM, K-split. C[32][512] = A[32][K] * W[512][K]^T.
// Grid: 256 blocks (one K-slice of 1280 each), 512 threads = 8 waves.
// Wave wv owns n in [wv*64, wv*64+64) (4 n-tiles of 16). Two b-tiles (32 rows).
// A-slice staged in LDS as fp16 in two 640-wide phases (41.5 KB).
#define KSLICE 1280
#define KPHASE 640
#define ALDS_STRIDE 648   // pad: 1296B row stride -> 2-way bank alias on b128 (free)

__global__ __launch_bounds__(512) void fc1_mfma(
    const _Float16* __restrict__ a,   // fcin [32][327680] fp16
    const float* __restrict__ w,      // fc1_w [512][327680] fp32
    float* __restrict__ part)         // [256][512][32] fp32 partials
{
    __shared__ _Float16 alds[32][ALDS_STRIDE];

    const int blk = blockIdx.x;
    const int tid = threadIdx.x;
    const int wv  = tid >> 6;
    const int ln  = tid & 63;
    const int lg  = ln >> 4;          // k-subgroup 0..3
    const int lr  = ln & 15;          // row-in-tile
    const int k0  = blk * KSLICE;

    floatx4 acc[2][4];
#pragma unroll
    for (int bt = 0; bt < 2; ++bt)
#pragma unroll
        for (int nt = 0; nt < 4; ++nt) acc[bt][nt] = (floatx4)0.0f;

    const float* wbase[4];
#pragma unroll
    for (int nt = 0; nt < 4; ++nt)
        wbase[nt] = w + (size_t)(wv * 64 + nt * 16 + lr) * FC1_IN + k0 + lg * 8;

    for (int p = 0; p < 2; ++p) {
        __syncthreads();   // waves done reading previous phase's LDS
        // stage a[32][p*640 .. +640) as half8: 2560 vectors / 512 threads
        for (int i = tid; i < 32 * 80; i += 512) {
            int r = i / 80;
            int c = (i - r * 80) * 8;
            *(half8*)&alds[r][c] =
                *(const half8*)&a[(size_t)r * FC1_IN + k0 + p * KPHASE + c];
        }
        __syncthreads();

        for (int kc = 0; kc < KPHASE / 32; ++kc) {
            half8 af0 = *(const half8*)&alds[lr][kc * 32 + lg * 8];
            half8 af1 = *(const half8*)&alds[16 + lr][kc * 32 + lg * 8];
#pragma unroll
            for (int nt = 0; nt < 4; ++nt) {
                const float* wp = wbase[nt] + p * KPHASE + kc * 32;
                float4 wlo = *(const float4*)wp;
                float4 whi = *(const float4*)(wp + 4);
                half8 bf;
                bf[0] = (_Float16)wlo.x; bf[1] = (_Float16)wlo.y;
                bf[2] = (_Float16)wlo.z; bf[3] = (_Float16)wlo.w;
                bf[4] = (_Float16)whi.x; bf[5] = (_Float16)whi.y;
                bf[6] = (_Float16)whi.z; bf[7] = (_Float16)whi.w;
                acc[0][nt] = __builtin_amdgcn_mfma_f32_16x16x32_f16(af0, bf, acc[0][nt], 0, 0, 0);
                acc[1][nt] = __builtin_amdgcn_mfma_f32_16x16x32_f16(af1, bf, acc[1][nt], 0, 0, 0);
            }
        }
    }

    // D[b][n]: b = bt*16 + lg*4 + r, n = wv*64 + nt*16 + lr. Write float4 per frag.
#pragma unroll
    for (int bt = 0; bt < 2; ++bt)
#pragma unroll
        for (int nt = 0; nt < 4; ++nt) {
            int n = wv * 64 + nt * 16 + lr;
            int b = bt * 16 + lg * 4;
            *(float4*)&part[((size_t)blk * FC1_OUT + n) * BATCH + b] =
                *(float4*)&acc[bt][nt];
        }
}

// Reduce 256 K-split partials, add bias, ReLU. z1 layout [32][512].
__global__ __launch_bounds__(256) void fc1_reduce(
    const float* __restrict__ part, const float* __restrict__ b1,
    float* __restrict__ z1)
{
    int e = blockIdx.x * 256 + threadIdx.x;  // < 16384; e = n*32 + b
    float s = 0.0f;
    for (int ks = 0; ks < 256; ++ks)
        s += part[(size_t)ks * (FC1_OUT * BATCH) + e];
    int n = e >> 5, b = e & 31;
    float v = s + b1[n];
    z1[(size_t)b * FC1_OUT + n] = v > 0.0f ? v : 0.0f;
}

// FC2 + sigmoid on column 2. out [32][3].
__global__ __launch_bounds__(128) void fc2_kernel(
    const float* __restrict__ z1, const float* __restrict__ w2,
    const float* __restrict__ b2, float* __restrict__ out)
{
    int t = threadIdx.x;
    if (t >= BATCH * OUT_DIM) return;
    int b = t / OUT_DIM, n = t - b * OUT_DIM;
    const float* zr = z1 + (size_t)b * FC1_OUT;
    const float* wr = w2 + (size_t)n * FC1_OUT;
    float acc = b2[n];
    for (int k = 0; k < FC1_OUT; ++k) acc += zr[k] * wr[k];
    if (n == 2) acc = sigm(acc);
    out[(size_t)b * OUT_DIM + n] = acc;
}

extern "C" void kernel_launch(void* const* d_in, const int* in_sizes, int n_in,
                              void* d_out, int out_size, void* d_ws, size_t ws_size,
                              hipStream_t stream) {
    const float* x   = (const float*)d_in[0];
    const float* cw0 = (const float*)d_in[1];
    const float* cb0 = (const float*)d_in[2];
    const float* cw1 = (const float*)d_in[3];
    const float* cb1 = (const float*)d_in[4];
    const float* w1  = (const float*)d_in[5];
    const float* b1  = (const float*)d_in[6];
    const float* w2  = (const float*)d_in[7];
    const float* b2  = (const float*)d_in[8];
    float* out = (float*)d_out;

    float* W = (float*)d_ws;
    const size_t S = (size_t)BATCH * HID * WIDTH;  // 524288 floats per state buffer
    float* h0buf[2] = { W + 0 * S, W + 4 * S };
    float* c0      = W + 1 * S;
    float* h1buf[2] = { W + 2 * S, W + 5 * S };
    float* c1      = W + 3 * S;
    _Float16* fcin = (_Float16*)(W + 6 * S);                  // [32][327680] fp16
    float* part    = (float*)(fcin + (size_t)BATCH * FC1_IN); // [256][512][32]
    float* z1      = part + (size_t)256 * FC1_OUT * BATCH;    // [32][512]

    hipMemsetAsync(W, 0, 4 * S * sizeof(float), stream);

    dim3 cgrid(BATCH, 4, 4);
    for (int t = 0; t < TSTEPS; ++t) {
        const float* h0p = h0buf[t & 1];
        float* h0n = h0buf[(t & 1) ^ 1];
        lstm_step<IN_DIM><<<cgrid, 256, 0, stream>>>(
            x + (size_t)t * IN_DIM * WIDTH, TSTEPS * IN_DIM * WIDTH,
            h0p, h0n, c0, cw0, cb0, nullptr, 0);

        const float* h1p = h1buf[t & 1];
        float* h1n = h1buf[(t & 1) ^ 1];
        lstm_step<HID><<<cgrid, 256, 0, stream>>>(
            h0n, HID * WIDTH,
            h1p, h1n, c1, cw1, cb1,
            fcin + (size_t)t * HID * WIDTH, FC1_IN);
    }

    fc1_mfma<<<256, 512, 0, stream>>>(fcin, w1, part);
    fc1_reduce<<<64, 256, 0, stream>>>(part, b1, z1);
    fc2_kernel<<<1, 128, 0, stream>>>(z1, w2, b2, out);
}

// Round 3
// 526.862 us; speedup vs baseline: 5.2624x; 3.1483x over previous
//
#include <hip/hip_runtime.h>
#include <hip/hip_bf16.h>
#include <cstddef>

// Problem constants
#define BATCH 32
#define TSTEPS 20
#define IN_DIM 3
#define WIDTH 256
#define HID 64
#define FC1_IN 327680   // HID * TSTEPS * WIDTH
#define FC1_OUT 512
#define OUT_DIM 3

typedef _Float16 half8 __attribute__((ext_vector_type(8)));
typedef float floatx4 __attribute__((ext_vector_type(4)));

__device__ __forceinline__ float sigm(float x) {
    return 1.0f / (1.0f + __expf(-x));
}
__device__ __forceinline__ float tanh_fast(float x) {
    return 1.0f - 2.0f / (__expf(2.0f * x) + 1.0f);
}

// ---------------- prep kernels (once per launch) ----------------

// wt0[kw][co][ci'=96]: ci' 0..2 = x ch (orig ci 0..2), 3..7 = 0,
// 8..71 = h ch (orig ci 3..66), 72..95 = 0. kh=1 slice only.
__global__ __launch_bounds__(256) void prep_w0(
    const float* __restrict__ cw0, _Float16* __restrict__ wt0)
{
    int e = blockIdx.x * 256 + threadIdx.x;   // < 256*96
    if (e >= 256 * 96) return;
    int co = e / 96, cip = e - co * 96;
    int ci = -1;
    if (cip < 3) ci = cip;
    else if (cip >= 8 && cip < 72) ci = cip - 5;
    float v[3] = {0.f, 0.f, 0.f};
    if (ci >= 0) {
#pragma unroll
        for (int kw = 0; kw < 3; ++kw)
            v[kw] = cw0[(size_t)(co * 67 + ci) * 9 + 3 + kw];
    }
#pragma unroll
    for (int kw = 0; kw < 3; ++kw)
        wt0[(size_t)(kw * 256 + co) * 96 + cip] = (_Float16)v[kw];
}

// wt1[kw][co][ci=128]: direct (z = [h0 64 | h1 64] matches cw1 ci order).
__global__ __launch_bounds__(256) void prep_w1(
    const float* __restrict__ cw1, _Float16* __restrict__ wt1)
{
    int e = blockIdx.x * 256 + threadIdx.x;   // < 256*128
    int co = e >> 7, ci = e & 127;
#pragma unroll
    for (int kw = 0; kw < 3; ++kw)
        wt1[(size_t)(kw * 256 + co) * 128 + ci] =
            (_Float16)cw1[(size_t)(co * 128 + ci) * 9 + 3 + kw];
}

// xT[t][b][w][8] fp16: ch 0..2 from x[b][t][ch][w], 3..7 = 0.
__global__ __launch_bounds__(256) void prep_x(
    const float* __restrict__ x, _Float16* __restrict__ xT)
{
    int e = blockIdx.x * 256 + threadIdx.x;   // < 20*32*256
    if (e >= TSTEPS * BATCH * WIDTH) return;
    int t = e / (BATCH * WIDTH);
    int rem = e - t * BATCH * WIDTH;
    int b = rem >> 8, w = rem & 255;
    half8 v = {};
#pragma unroll
    for (int ci = 0; ci < 3; ++ci)
        v[ci] = (_Float16)x[(size_t)((b * TSTEPS + t) * IN_DIM + ci) * WIDTH + w];
    *(half8*)&xT[(size_t)e * 8] = v;
}

// ---------------- fused ConvLSTM step, MFMA ----------------
// gates[n=(b,w)][co] = sum_{kw,ci} z[w+kw-1][ci] * wt[kw][co][ci], z=[xin|hprev|pad].
// Grid (32 b, 8 wtiles), 256 threads = 4 waves; wave g owns gate g (64 co).
// CIPAD: padded ci count (96 layer0 / 128 layer1); XCH: xin channels (8 / 64).
template <int CIPAD, int XCH>
__global__ __launch_bounds__(256) void conv_step(
    const _Float16* __restrict__ xin,    // [B*W][XCH]
    const _Float16* __restrict__ hprev,  // [B*W][64]
    _Float16* __restrict__ hnew,         // [B*W][64]
    float* __restrict__ cst,             // [B*W][64], in place (element-owned)
    const _Float16* __restrict__ wt,     // [3][256][CIPAD]
    const float* __restrict__ cb,        // [256]
    _Float16* __restrict__ fcout, int t) // fcin [B][T][64][W] or null
{
    constexpr int ZSTR = CIPAD + 8;      // +16B row pad -> 2-way bank alias (free)
    constexpr int NKF  = CIPAD / 32;
    constexpr int XC8  = XCH / 8;
    constexpr int NC8  = CIPAD / 8;

    __shared__ _Float16 zlds[34 * ZSTR];
    __shared__ float glds[32 * 257];     // stride 257 -> conflict-free col reads
    __shared__ float cblds[256];

    const int b   = blockIdx.x;
    const int w0  = blockIdx.y * 32;
    const int tid = threadIdx.x;

    cblds[tid] = cb[tid];

    // stage z rows j=0..33 (w = w0-1+j): [xin ch | h ch | zero pad]
    for (int i = tid; i < 34 * NC8; i += 256) {
        int j = i / NC8, c = i - j * NC8;
        int wg = w0 - 1 + j;
        half8 v = {};
        if (wg >= 0 && wg < WIDTH) {
            size_t pos = (size_t)b * WIDTH + wg;
            if (c < XC8)          v = *(const half8*)&xin[pos * XCH + c * 8];
            else if (c < XC8 + 8) v = *(const half8*)&hprev[pos * 64 + (c - XC8) * 8];
        }
        *(half8*)&zlds[j * ZSTR + c * 8] = v;
    }
    __syncthreads();

    const int g  = tid >> 6;   // wave index = gate (i,f,o,g)
    const int ln = tid & 63;
    const int lr = ln & 15;    // A-row / B-col lane index
    const int kg = ln >> 4;    // k-subgroup

    floatx4 acc[2][4];
#pragma unroll
    for (int nf = 0; nf < 2; ++nf)
#pragma unroll
        for (int cf = 0; cf < 4; ++cf) acc[nf][cf] = (floatx4)0.0f;

#pragma unroll
    for (int kw = 0; kw < 3; ++kw) {
#pragma unroll
        for (int kf = 0; kf < NKF; ++kf) {
            int kb = kf * 32 + kg * 8;
            half8 a0 = *(const half8*)&zlds[(lr + kw) * ZSTR + kb];
            half8 a1 = *(const half8*)&zlds[(lr + kw + 16) * ZSTR + kb];
#pragma unroll
            for (int cf = 0; cf < 4; ++cf) {
                half8 bf = *(const half8*)&wt[
                    (size_t)((kw * 256) + g * 64 + cf * 16 + lr) * CIPAD + kb];
                acc[0][cf] = __builtin_amdgcn_mfma_f32_16x16x32_f16(a0, bf, acc[0][cf], 0, 0, 0);
                acc[1][cf] = __builtin_amdgcn_mfma_f32_16x16x32_f16(a1, bf, acc[1][cf], 0, 0, 0);
            }
        }
    }

    // D[row=n][col=co]: row = nf*16 + kg*4 + r, col = g*64 + cf*16 + lr
#pragma unroll
    for (int nf = 0; nf < 2; ++nf)
#pragma unroll
        for (int cf = 0; cf < 4; ++cf)
#pragma unroll
            for (int r = 0; r < 4; ++r)
                glds[(nf * 16 + kg * 4 + r) * 257 + g * 64 + cf * 16 + lr] = acc[nf][cf][r];
    __syncthreads();

    // epilogue: gate nonlinearities + state update. thread = (wloc, 8 hc)
    const int wloc = tid & 31;
    const int hcg  = tid >> 5;
    const int wg   = w0 + wloc;
    const size_t pos = (size_t)b * WIDTH + wg;

    float cin[8];
    *(float4*)&cin[0] = *(const float4*)&cst[pos * 64 + hcg * 8];
    *(float4*)&cin[4] = *(const float4*)&cst[pos * 64 + hcg * 8 + 4];

    float cno[8];
    half8 hb;
#pragma unroll
    for (int j = 0; j < 8; ++j) {
        int hc = hcg * 8 + j;
        float gi = glds[wloc * 257 + hc]       + cblds[hc];
        float gf = glds[wloc * 257 + 64 + hc]  + cblds[64 + hc];
        float go = glds[wloc * 257 + 128 + hc] + cblds[128 + hc];
        float gg = glds[wloc * 257 + 192 + hc] + cblds[192 + hc];
        float cn = sigm(gf) * cin[j] + sigm(gi) * tanh_fast(gg);
        cno[j] = cn;
        hb[j] = (_Float16)(sigm(go) * tanh_fast(cn));
    }
    *(float4*)&cst[pos * 64 + hcg * 8]     = *(float4*)&cno[0];
    *(float4*)&cst[pos * 64 + hcg * 8 + 4] = *(float4*)&cno[4];
    *(half8*)&hnew[pos * 64 + hcg * 8] = hb;

    if (fcout) {
#pragma unroll
        for (int j = 0; j < 8; ++j) {
            int hc = hcg * 8 + j;
            fcout[(size_t)((b * TSTEPS + t) * HID + hc) * WIDTH + wg] = hb[j];
        }
    }
}

// ---------------- FC1 fp16 MFMA GEMM, K-split ----------------
#define KSLICE 1280
#define KPHASE 640
#define ALDS_STRIDE 648

__global__ __launch_bounds__(512) void fc1_mfma(
    const _Float16* __restrict__ a,   // fcin [32][327680] fp16
    const float* __restrict__ w,      // fc1_w [512][327680] fp32
    float* __restrict__ part)         // [256][512][32] fp32 partials
{
    __shared__ _Float16 alds[32][ALDS_STRIDE];

    const int blk = blockIdx.x;
    const int tid = threadIdx.x;
    const int wv  = tid >> 6;
    const int ln  = tid & 63;
    const int lg  = ln >> 4;
    const int lr  = ln & 15;
    const int k0  = blk * KSLICE;

    floatx4 acc[2][4];
#pragma unroll
    for (int bt = 0; bt < 2; ++bt)
#pragma unroll
        for (int nt = 0; nt < 4; ++nt) acc[bt][nt] = (floatx4)0.0f;

    const float* wbase[4];
#pragma unroll
    for (int nt = 0; nt < 4; ++nt)
        wbase[nt] = w + (size_t)(wv * 64 + nt * 16 + lr) * FC1_IN + k0 + lg * 8;

    for (int p = 0; p < 2; ++p) {
        __syncthreads();
        for (int i = tid; i < 32 * 80; i += 512) {
            int r = i / 80;
            int c = (i - r * 80) * 8;
            *(half8*)&alds[r][c] =
                *(const half8*)&a[(size_t)r * FC1_IN + k0 + p * KPHASE + c];
        }
        __syncthreads();

        for (int kc = 0; kc < KPHASE / 32; ++kc) {
            half8 af0 = *(const half8*)&alds[lr][kc * 32 + lg * 8];
            half8 af1 = *(const half8*)&alds[16 + lr][kc * 32 + lg * 8];
#pragma unroll
            for (int nt = 0; nt < 4; ++nt) {
                const float* wp = wbase[nt] + p * KPHASE + kc * 32;
                float4 wlo = *(const float4*)wp;
                float4 whi = *(const float4*)(wp + 4);
                half8 bf;
                bf[0] = (_Float16)wlo.x; bf[1] = (_Float16)wlo.y;
                bf[2] = (_Float16)wlo.z; bf[3] = (_Float16)wlo.w;
                bf[4] = (_Float16)whi.x; bf[5] = (_Float16)whi.y;
                bf[6] = (_Float16)whi.z; bf[7] = (_Float16)whi.w;
                acc[0][nt] = __builtin_amdgcn_mfma_f32_16x16x32_f16(af0, bf, acc[0][nt], 0, 0, 0);
                acc[1][nt] = __builtin_amdgcn_mfma_f32_16x16x32_f16(af1, bf, acc[1][nt], 0, 0, 0);
            }
        }
    }

#pragma unroll
    for (int bt = 0; bt < 2; ++bt)
#pragma unroll
        for (int nt = 0; nt < 4; ++nt) {
            int n = wv * 64 + nt * 16 + lr;
            int b = bt * 16 + lg * 4;
            *(float4*)&part[((size_t)blk * FC1_OUT + n) * BATCH + b] =
                *(float4*)&acc[bt][nt];
        }
}

__global__ __launch_bounds__(256) void fc1_reduce(
    const float* __restrict__ part, const float* __restrict__ b1,
    float* __restrict__ z1)
{
    int e = blockIdx.x * 256 + threadIdx.x;  // e = n*32 + b
    float s = 0.0f;
    for (int ks = 0; ks < 256; ++ks)
        s += part[(size_t)ks * (FC1_OUT * BATCH) + e];
    int n = e >> 5, b = e & 31;
    float v = s + b1[n];
    z1[(size_t)b * FC1_OUT + n] = v > 0.0f ? v : 0.0f;
}

__global__ __launch_bounds__(128) void fc2_kernel(
    const float* __restrict__ z1, const float* __restrict__ w2,
    const float* __restrict__ b2, float* __restrict__ out)
{
    int t = threadIdx.x;
    if (t >= BATCH * OUT_DIM) return;
    int b = t / OUT_DIM, n = t - b * OUT_DIM;
    const float* zr = z1 + (size_t)b * FC1_OUT;
    const float* wr = w2 + (size_t)n * FC1_OUT;
    float acc = b2[n];
    for (int k = 0; k < FC1_OUT; ++k) acc += zr[k] * wr[k];
    if (n == 2) acc = sigm(acc);
    out[(size_t)b * OUT_DIM + n] = acc;
}

extern "C" void kernel_launch(void* const* d_in, const int* in_sizes, int n_in,
                              void* d_out, int out_size, void* d_ws, size_t ws_size,
                              hipStream_t stream) {
    const float* x   = (const float*)d_in[0];
    const float* cw0 = (const float*)d_in[1];
    const float* cb0 = (const float*)d_in[2];
    const float* cw1 = (const float*)d_in[3];
    const float* cb1 = (const float*)d_in[4];
    const float* w1  = (const float*)d_in[5];
    const float* b1  = (const float*)d_in[6];
    const float* w2  = (const float*)d_in[7];
    const float* b2  = (const float*)d_in[8];
    float* out = (float*)d_out;

    const size_t S2 = (size_t)BATCH * WIDTH * HID;   // 524288 elements
    char* p = (char*)d_ws;
    auto alloc = [&](size_t bytes) { char* r = p; p += (bytes + 255) & ~(size_t)255; return r; };

    // zero block: h0a, h1a, c0, c1 (contiguous, 6 MB)
    _Float16* h0a = (_Float16*)alloc(S2 * 2);
    _Float16* h1a = (_Float16*)alloc(S2 * 2);
    float*    c0  = (float*)alloc(S2 * 4);
    float*    c1  = (float*)alloc(S2 * 4);
    size_t zero_bytes = (size_t)(p - (char*)d_ws);

    _Float16* h0b = (_Float16*)alloc(S2 * 2);
    _Float16* h1b = (_Float16*)alloc(S2 * 2);
    _Float16* wt0 = (_Float16*)alloc((size_t)3 * 256 * 96 * 2);
    _Float16* wt1 = (_Float16*)alloc((size_t)3 * 256 * 128 * 2);
    _Float16* xT  = (_Float16*)alloc((size_t)TSTEPS * BATCH * WIDTH * 8 * 2);
    _Float16* fcin = (_Float16*)alloc((size_t)BATCH * FC1_IN * 2);
    float* part = (float*)alloc((size_t)256 * FC1_OUT * BATCH * 4);
    float* z1   = (float*)alloc((size_t)BATCH * FC1_OUT * 4);

    hipMemsetAsync(d_ws, 0, zero_bytes, stream);
    prep_w0<<<96, 256, 0, stream>>>(cw0, wt0);
    prep_w1<<<128, 256, 0, stream>>>(cw1, wt1);
    prep_x<<<(TSTEPS * BATCH * WIDTH + 255) / 256, 256, 0, stream>>>(x, xT);

    dim3 cgrid(BATCH, 8);
    for (int t = 0; t < TSTEPS; ++t) {
        _Float16* h0r = (t & 1) ? h0b : h0a;
        _Float16* h0w = (t & 1) ? h0a : h0b;
        conv_step<96, 8><<<cgrid, 256, 0, stream>>>(
            xT + (size_t)t * BATCH * WIDTH * 8, h0r, h0w, c0, wt0, cb0, nullptr, 0);

        _Float16* h1r = (t & 1) ? h1b : h1a;
        _Float16* h1w = (t & 1) ? h1a : h1b;
        conv_step<128, 64><<<cgrid, 256, 0, stream>>>(
            h0w, h1r, h1w, c1, wt1, cb1, fcin, t);
    }

    fc1_mfma<<<256, 512, 0, stream>>>(fcin, w1, part);
    fc1_reduce<<<64, 256, 0, stream>>>(part, b1, z1);
    fc2_kernel<<<1, 128, 0, stream>>>(z1, w2, b2, out);
}